// Round 7
// baseline (329.270 us; speedup 1.0000x reference)
//
#include <hip/hip_runtime.h>
#include <hip/hip_bf16.h>
#include <cstdint>
#include <cstddef>

typedef unsigned short u16;
typedef __attribute__((ext_vector_type(8))) short s8v;    // 8 x bf16 = 4 VGPR
typedef __attribute__((ext_vector_type(4))) float f4v;    // 16x16 MFMA acc
typedef __attribute__((ext_vector_type(8))) u16 u16x8;
typedef __attribute__((ext_vector_type(4))) uint32_t u32x4;

#define AS1 __attribute__((address_space(1)))
#define AS3 __attribute__((address_space(3)))

// ---- constants ----
#define BATCH 16
#define SEQ   1024
#define EMBED 768
#define HEADS 12
#define DH    64
#define MTOT  (BATCH*SEQ)       // 16384

__device__ __forceinline__ u16 f2bf(float f) {      // RNE fp32 -> bf16
    union { float f; uint32_t u; } v; v.f = f;
    uint32_t r = v.u + 0x7fffu + ((v.u >> 16) & 1u);
    return (u16)(r >> 16);
}

__device__ __forceinline__ void gll16(const u16* g, u16* l) {
    __builtin_amdgcn_global_load_lds((AS1 void*)g, (AS3 void*)l, 16, 0, 0);
}

// ---------------- fused pack ----------------
// x -> bf16 (coalesced); weights transpose+bf16 via 64x64 LDS tiles (round-6
// verified); biases. Wq/bq pre-scaled by 0.125 (folds 1/sqrt(Dh) into Q proj).
#define XBLOCKS 12288
#define TBLOCKS 576          // 432 QKV tiles (36 n x 12 k) + 144 Wo tiles (12 x 12)
__global__ void k_pack(const float* __restrict__ x, u16* __restrict__ xb, int nx,
                       const float* __restrict__ Wq, const float* __restrict__ Wk,
                       const float* __restrict__ Wv, const float* __restrict__ Wo,
                       const float* __restrict__ bq, const float* __restrict__ bk,
                       const float* __restrict__ bv,
                       u16* __restrict__ wqkvT, u16* __restrict__ woT,
                       float* __restrict__ bqkv)
{
    __shared__ __attribute__((aligned(16))) u16 ts[64 * 80];
    const int tid = threadIdx.x;
    if (blockIdx.x < XBLOCKS) {
        int i = (blockIdx.x * 256 + tid) * 4;
        if (i + 3 < nx) {
            float4 f = *(const float4*)(x + i);
            ushort4 o;
            o.x = f2bf(f.x); o.y = f2bf(f.y); o.z = f2bf(f.z); o.w = f2bf(f.w);
            *(ushort4*)(xb + i) = o;
        }
        return;
    }
    int tb = blockIdx.x - XBLOCKS;
    if (tb < TBLOCKS) {
        // 64x64 tile transpose: out[n][k] = src[k][nn] * sc (bf16)
        const float* src; u16* dst; int n0, k0, nn0; float sc;
        if (tb < 432) {
            int nt = tb % 36, kt = tb / 36;
            n0 = nt * 64; k0 = kt * 64; dst = wqkvT;
            if (n0 < 768)       { src = Wq; nn0 = n0;        sc = 0.125f; }
            else if (n0 < 1536) { src = Wk; nn0 = n0 - 768;  sc = 1.0f;   }
            else                { src = Wv; nn0 = n0 - 1536; sc = 1.0f;   }
        } else {
            int tb2 = tb - 432;
            int nt = tb2 % 12, kt = tb2 / 12;
            n0 = nt * 64; k0 = kt * 64; nn0 = n0; sc = 1.0f;
            src = Wo; dst = woT;
        }
        const int r = tid >> 2, cb = (tid & 3) * 16;
#pragma unroll
        for (int i = 0; i < 4; ++i) {
            float4 f = *(const float4*)(src + (size_t)(k0 + r) * 768 + nn0 + cb + i * 4);
            ts[(cb + i * 4 + 0) * 80 + r] = f2bf(f.x * sc);
            ts[(cb + i * 4 + 1) * 80 + r] = f2bf(f.y * sc);
            ts[(cb + i * 4 + 2) * 80 + r] = f2bf(f.z * sc);
            ts[(cb + i * 4 + 3) * 80 + r] = f2bf(f.w * sc);
        }
        __syncthreads();
#pragma unroll
        for (int j = 0; j < 2; ++j) {
            u16x8 tv = *(const u16x8*)(ts + r * 80 + cb + j * 8);
            *(u16x8*)(dst + (size_t)(n0 + r) * 768 + k0 + cb + j * 8) = tv;
        }
        return;
    }
    int t3 = (tb - TBLOCKS) * 256 + tid;
    if (t3 < 2304) {
        bqkv[t3] = (t3 < 768) ? bq[t3] * 0.125f
                 : ((t3 < 1536) ? bk[t3 - 768] : bv[t3 - 1536]);
    }
}

// ---------------- GEMM: C[M x N] = A[M x 768] * BT[N x 768]^T + bias ----------------
// Round-7: 128x128 tile, BK=64 (12 K-steps, half the vmcnt(0)+barrier drains of
// BK=32), 256 thr (4 waves 2x2), wave tile 64x64; 32 MFMA 16x16x32 per K-step.
// LDS 32 KB. XOR-swizzled staging lifted verbatim from the round-3/5-verified
// gemm8: global source pre-swizzled chunk ((tid&7)^((tid>>3)&7)), linear gll16
// dest; reads use slot (quad^(l15&7)) / ((4+quad)^(l15&7)) -> conflict-free
// (row stride 128B would otherwise be a 16-way conflict).
// MODE 0: N=2304, split cols into q/k/v bf16 buffers. MODE 1: N=768, fp32 out.
template<int MODE>
__global__ __launch_bounds__(256) void k_gemm(
    const u16* __restrict__ A, const u16* __restrict__ BT,
    const float* __restrict__ bias,
    u16* __restrict__ oq, u16* __restrict__ okk, u16* __restrict__ ov,
    float* __restrict__ of)
{
    __shared__ __attribute__((aligned(16))) u16 As[128 * 64];   // 16 KB
    __shared__ __attribute__((aligned(16))) u16 Bs[128 * 64];   // 16 KB
    const int tid = threadIdx.x;
    const int m0 = blockIdx.x * 128;
    const int n0 = blockIdx.y * 128;
    const int wv = tid >> 6;
    const int ln = tid & 63;
    const int l15 = ln & 15, quad = ln >> 4;
    const int wm = (wv >> 1) * 64, wn = (wv & 1) * 64;

    // staging: iter i covers rows i*32 + (tid>>3), LDS chunk tid&7 (linear dest),
    // global source chunk = (tid&7) ^ ((tid>>3)&7)  [pre-swizzle, rule #21]
    const int srow = tid >> 3;
    const int schnk = ((tid & 7) ^ (srow & 7)) * 8;
    const u16* gA = A + (size_t)(m0 + srow) * 768 + schnk;
    const u16* gB = BT + (size_t)(n0 + srow) * 768 + schnk;
    u16* lA = As + wv * 512;            // + i*2048 per iter (lane adds ln*16B)
    u16* lB = Bs + wv * 512;

    // read-side swizzled chunk slots (u16 offsets within a 64-u16 row)
    const int sl0 = ((quad)     ^ (l15 & 7)) * 8;   // k-half 0 (k 0..31)
    const int sl1 = ((4 + quad) ^ (l15 & 7)) * 8;   // k-half 1 (k 32..63)

    f4v acc[4][4] = {};

    for (int kt = 0; kt < 12; ++kt) {
        const int ko = kt * 64;
#pragma unroll
        for (int i = 0; i < 4; ++i) {
            gll16(gA + (size_t)i * 32 * 768 + ko, lA + i * 2048);
            gll16(gB + (size_t)i * 32 * 768 + ko, lB + i * 2048);
        }
        __syncthreads();

        s8v aF[4][2];
#pragma unroll
        for (int i = 0; i < 4; ++i) {
            const u16* base = As + (wm + i * 16 + l15) * 64;
            aF[i][0] = *(const s8v*)(base + sl0);
            aF[i][1] = *(const s8v*)(base + sl1);
        }
#pragma unroll
        for (int j = 0; j < 4; ++j) {
            const u16* base = Bs + (wn + j * 16 + l15) * 64;
            s8v bF0 = *(const s8v*)(base + sl0);
            s8v bF1 = *(const s8v*)(base + sl1);
#pragma unroll
            for (int i = 0; i < 4; ++i) {
                acc[i][j] = __builtin_amdgcn_mfma_f32_16x16x32_bf16(aF[i][0], bF0, acc[i][j], 0, 0, 0);
                acc[i][j] = __builtin_amdgcn_mfma_f32_16x16x32_bf16(aF[i][1], bF1, acc[i][j], 0, 0, 0);
            }
        }
        __syncthreads();
    }

    // epilogue: C/D layout col = l15, row = quad*4 + reg (verified)
#pragma unroll
    for (int j = 0; j < 4; ++j) {
        int n = n0 + wn + j * 16 + l15;
        float bs = bias[n];
        if (MODE == 0) {
            u16* dst; int nn;
            if (n < 768)       { dst = oq;  nn = n; }
            else if (n < 1536) { dst = okk; nn = n - 768; }
            else               { dst = ov;  nn = n - 1536; }
#pragma unroll
            for (int i = 0; i < 4; ++i) {
                int mrow = m0 + wm + i * 16 + quad * 4;
#pragma unroll
                for (int rg = 0; rg < 4; ++rg)
                    dst[(size_t)(mrow + rg) * 768 + nn] = f2bf(acc[i][j][rg] + bs);
            }
        } else {
#pragma unroll
            for (int i = 0; i < 4; ++i) {
                int mrow = m0 + wm + i * 16 + quad * 4;
#pragma unroll
                for (int rg = 0; rg < 4; ++rg)
                    of[(size_t)(mrow + rg) * 768 + n] = acc[i][j][rg] + bs;
            }
        }
    }
}

// ---------------- V transpose: (192,1024,64) -> (192,64,1024) ----------------
__global__ void k_transpose_v(const u16* __restrict__ v, u16* __restrict__ vt) {
    __shared__ __attribute__((aligned(16))) u16 ts[64 * 80];
    int g = blockIdx.x >> 4;
    int l0 = (blockIdx.x & 15) << 6;
    const u16* vg = v + (size_t)g * 65536;
    u16* vtg = vt + (size_t)g * 65536;
    int tid = threadIdx.x;
#pragma unroll
    for (int c = tid; c < 512; c += 256) {
        int l = c >> 3, d0 = (c & 7) * 8;
        *(uint4*)(ts + l * 80 + d0) = *(const uint4*)(vg + (size_t)(l0 + l) * 64 + d0);
    }
    __syncthreads();
#pragma unroll
    for (int c = tid; c < 512; c += 256) {
        int d = c >> 3, lc = (c & 7) * 8;
        u16x8 tv;
#pragma unroll
        for (int i = 0; i < 8; ++i) tv[i] = ts[(lc + i) * 80 + d];
        *(u16x8*)(vtg + (size_t)d * 1024 + l0 + lc) = tv;
    }
}

// ---------------- flash attention per (group, 128-row q-tile) ----------------
// Round-6 verified: 2 q-row-sets per wave (shared K/V fragment reads), T12
// in-register softmax, T14 raw-barrier prefetch. q pre-scaled by 1/8.
#define KS2(r_, c_) ( ((r_) << 6) + (((((c_) >> 3) ^ ((r_) & 7)) & 7) << 3) + ((c_) & 7) )

__global__ __launch_bounds__(256) void k_attn(
    const u16* __restrict__ qb, const u16* __restrict__ kb,
    const u16* __restrict__ vt, u16* __restrict__ ctx)
{
    __shared__ __attribute__((aligned(16))) u16 Ks[128 * 64];    // 16 KB, XOR-swizzled
    __shared__ __attribute__((aligned(16))) u16 Vts[64 * 136];   // 17408 B

    const int g = blockIdx.x >> 3;
    const int q0 = (blockIdx.x & 7) << 7;
    const int tid = threadIdx.x, wv = tid >> 6;
    const int ln = tid & 63, l15 = ln & 15, quad = ln >> 4;
    const u16* qg = qb + (size_t)g * 65536;
    const u16* kg = kb + (size_t)g * 65536;
    const u16* vtg = vt + (size_t)g * 65536;

    const int krr = tid >> 3, kcb = (tid & 7) * 8;       // K: +i*32 rows
    const int vd = tid >> 4, vc0 = (tid & 15) * 8;       // Vt: +i*16 d-rows
    const u16* kgp = kg + (size_t)krr * 64 + kcb;
    const u16* vgp = vtg + (size_t)vd * 1024 + vc0;

    uint4 kr0 = *(const uint4*)(kgp);
    uint4 kr1 = *(const uint4*)(kgp + 2048);
    uint4 kr2 = *(const uint4*)(kgp + 4096);
    uint4 kr3 = *(const uint4*)(kgp + 6144);
    uint4 vr0 = *(const uint4*)(vgp);
    uint4 vr1 = *(const uint4*)(vgp + 16384);
    uint4 vr2 = *(const uint4*)(vgp + 32768);
    uint4 vr3 = *(const uint4*)(vgp + 49152);

    const u16* qrow = qg + (size_t)(q0 + wv * 32 + l15) * 64 + quad * 8;
    s8v aQ00 = *(const s8v*)qrow;
    s8v aQ01 = *(const s8v*)(qrow + 32);
    s8v aQ10 = *(const s8v*)(qrow + 1024);        // +16 rows * 64
    s8v aQ11 = *(const s8v*)(qrow + 1024 + 32);

    f4v o0[4] = {}, o1[4] = {};
    float rsum0 = 0.f, rsum1 = 0.f;

    for (int jt = 0; jt < 8; ++jt) {
        __builtin_amdgcn_s_barrier();
        __builtin_amdgcn_sched_barrier(0);

        *(uint4*)(Ks + KS2(krr,      kcb)) = kr0;
        *(uint4*)(Ks + KS2(krr + 32, kcb)) = kr1;
        *(uint4*)(Ks + KS2(krr + 64, kcb)) = kr2;
        *(uint4*)(Ks + KS2(krr + 96, kcb)) = kr3;
        *(uint4*)(Vts + (vd     ) * 136 + vc0) = vr0;
        *(uint4*)(Vts + (vd + 16) * 136 + vc0) = vr1;
        *(uint4*)(Vts + (vd + 32) * 136 + vc0) = vr2;
        *(uint4*)(Vts + (vd + 48) * 136 + vc0) = vr3;

        if (jt < 7) {
            const size_t koff = (size_t)(jt + 1) * 8192;   // 128 rows * 64
            const int voff = (jt + 1) * 128;
            kr0 = *(const uint4*)(kgp + koff);
            kr1 = *(const uint4*)(kgp + koff + 2048);
            kr2 = *(const uint4*)(kgp + koff + 4096);
            kr3 = *(const uint4*)(kgp + koff + 6144);
            vr0 = *(const uint4*)(vgp + voff);
            vr1 = *(const uint4*)(vgp + voff + 16384);
            vr2 = *(const uint4*)(vgp + voff + 32768);
            vr3 = *(const uint4*)(vgp + voff + 49152);
        }

        asm volatile("s_waitcnt lgkmcnt(0)" ::: "memory");
        __builtin_amdgcn_s_barrier();
        __builtin_amdgcn_sched_barrier(0);

        f4v s0[8], s1[8];
        __builtin_amdgcn_s_setprio(1);
#pragma unroll
        for (int ns = 0; ns < 8; ++ns) {
            int rK = ns * 16 + l15;
            s8v b0 = *(const s8v*)(Ks + KS2(rK, quad * 8));
            s8v b1 = *(const s8v*)(Ks + KS2(rK, quad * 8 + 32));
            f4v t0 = {};
            t0 = __builtin_amdgcn_mfma_f32_16x16x32_bf16(b0, aQ00, t0, 0, 0, 0);
            t0 = __builtin_amdgcn_mfma_f32_16x16x32_bf16(b1, aQ01, t0, 0, 0, 0);
            s0[ns] = t0;
            f4v t1 = {};
            t1 = __builtin_amdgcn_mfma_f32_16x16x32_bf16(b0, aQ10, t1, 0, 0, 0);
            t1 = __builtin_amdgcn_mfma_f32_16x16x32_bf16(b1, aQ11, t1, 0, 0, 0);
            s1[ns] = t1;
        }
        __builtin_amdgcn_s_setprio(0);

        s8v aP0[4], aP1[4];
#pragma unroll
        for (int ns = 0; ns < 8; ++ns)
#pragma unroll
            for (int rg = 0; rg < 4; ++rg) {
                float p = __expf(s0[ns][rg]);
                s0[ns][rg] = p;
                rsum0 += p;
            }
#pragma unroll
        for (int ks = 0; ks < 4; ++ks) {
            uint32_t a0, a1, c0, c1;
            asm("v_cvt_pk_bf16_f32 %0, %1, %2" : "=v"(a0) : "v"(s0[2*ks][0]),   "v"(s0[2*ks][1]));
            asm("v_cvt_pk_bf16_f32 %0, %1, %2" : "=v"(a1) : "v"(s0[2*ks][2]),   "v"(s0[2*ks][3]));
            asm("v_cvt_pk_bf16_f32 %0, %1, %2" : "=v"(c0) : "v"(s0[2*ks+1][0]), "v"(s0[2*ks+1][1]));
            asm("v_cvt_pk_bf16_f32 %0, %1, %2" : "=v"(c1) : "v"(s0[2*ks+1][2]), "v"(s0[2*ks+1][3]));
            asm("v_permlane32_swap_b32 %0, %1" : "+v"(a0), "+v"(c0));
            asm("v_permlane16_swap_b32 %0, %1" : "+v"(a0), "+v"(c0));
            asm("v_permlane32_swap_b32 %0, %1" : "+v"(a1), "+v"(c1));
            asm("v_permlane16_swap_b32 %0, %1" : "+v"(a1), "+v"(c1));
            u32x4 pk; pk.x = a0; pk.y = a1; pk.z = c0; pk.w = c1;
            aP0[ks] = __builtin_bit_cast(s8v, pk);
        }
#pragma unroll
        for (int ns = 0; ns < 8; ++ns)
#pragma unroll
            for (int rg = 0; rg < 4; ++rg) {
                float p = __expf(s1[ns][rg]);
                s1[ns][rg] = p;
                rsum1 += p;
            }
#pragma unroll
        for (int ks = 0; ks < 4; ++ks) {
            uint32_t a0, a1, c0, c1;
            asm("v_cvt_pk_bf16_f32 %0, %1, %2" : "=v"(a0) : "v"(s1[2*ks][0]),   "v"(s1[2*ks][1]));
            asm("v_cvt_pk_bf16_f32 %0, %1, %2" : "=v"(a1) : "v"(s1[2*ks][2]),   "v"(s1[2*ks][3]));
            asm("v_cvt_pk_bf16_f32 %0, %1, %2" : "=v"(c0) : "v"(s1[2*ks+1][0]), "v"(s1[2*ks+1][1]));
            asm("v_cvt_pk_bf16_f32 %0, %1, %2" : "=v"(c1) : "v"(s1[2*ks+1][2]), "v"(s1[2*ks+1][3]));
            asm("v_permlane32_swap_b32 %0, %1" : "+v"(a0), "+v"(c0));
            asm("v_permlane16_swap_b32 %0, %1" : "+v"(a0), "+v"(c0));
            asm("v_permlane32_swap_b32 %0, %1" : "+v"(a1), "+v"(c1));
            asm("v_permlane16_swap_b32 %0, %1" : "+v"(a1), "+v"(c1));
            u32x4 pk; pk.x = a0; pk.y = a1; pk.z = c0; pk.w = c1;
            aP1[ks] = __builtin_bit_cast(s8v, pk);
        }

        __builtin_amdgcn_s_setprio(1);
#pragma unroll
        for (int ks = 0; ks < 4; ++ks)
#pragma unroll
            for (int ds = 0; ds < 4; ++ds) {
                s8v bV = *(const s8v*)(Vts + (ds * 16 + l15) * 136 + ks * 32 + quad * 8);
                o0[ds] = __builtin_amdgcn_mfma_f32_16x16x32_bf16(aP0[ks], bV, o0[ds], 0, 0, 0);
                o1[ds] = __builtin_amdgcn_mfma_f32_16x16x32_bf16(aP1[ks], bV, o1[ds], 0, 0, 0);
            }
        __builtin_amdgcn_s_setprio(0);
    }

    rsum0 += __shfl_xor(rsum0, 16, 64);
    rsum0 += __shfl_xor(rsum0, 32, 64);
    rsum1 += __shfl_xor(rsum1, 16, 64);
    rsum1 += __shfl_xor(rsum1, 32, 64);

    const int b = g / 12, h = g % 12;
    u16* cbase = ctx + (size_t)b * 786432 + h * 64;
#pragma unroll
    for (int rg = 0; rg < 4; ++rg) {
        int row0 = q0 + wv * 32 + quad * 4 + rg;
        float inv0 = 1.0f / __shfl(rsum0, 20 * quad + rg, 64);
#pragma unroll
        for (int ds = 0; ds < 4; ++ds)
            cbase[(size_t)row0 * 768 + ds * 16 + l15] = f2bf(o0[ds][rg] * inv0);
        int row1 = row0 + 16;
        float inv1 = 1.0f / __shfl(rsum1, 20 * quad + rg, 64);
#pragma unroll
        for (int ds = 0; ds < 4; ++ds)
            cbase[(size_t)row1 * 768 + ds * 16 + l15] = f2bf(o1[ds][rg] * inv1);
    }
}

// ---------------- launcher ----------------
extern "C" void kernel_launch(void* const* d_in, const int* in_sizes, int n_in,
                              void* d_out, int out_size, void* d_ws, size_t ws_size,
                              hipStream_t stream) {
    const float* x  = (const float*)d_in[0];
    const float* Wq = (const float*)d_in[1];
    const float* bq = (const float*)d_in[2];
    const float* Wk = (const float*)d_in[3];
    const float* bk = (const float*)d_in[4];
    const float* Wv = (const float*)d_in[5];
    const float* bv = (const float*)d_in[6];
    const float* Wo = (const float*)d_in[7];
    const float* bo = (const float*)d_in[8];
    float* out = (float*)d_out;

    const size_t NTOK = (size_t)MTOT * EMBED;          // 12,582,912
    char* w = (char*)d_ws;
    u16* xb    = (u16*)w;              w += NTOK * 2;  // x bf16; reused as ctx
    u16* qb    = (u16*)w;              w += NTOK * 2;
    u16* kb    = (u16*)w;              w += NTOK * 2;
    u16* vb    = (u16*)w;              w += NTOK * 2;
    u16* vtb   = (u16*)w;              w += NTOK * 2;
    u16* wqkvT = (u16*)w;              w += (size_t)2304 * 768 * 2;
    u16* woT   = (u16*)w;              w += (size_t)768 * 768 * 2;
    float* bqkv = (float*)w;           w += 2304 * 4;
    u16* ctx = xb;                                      // reuse (x dead after GEMM1)

    k_pack<<<XBLOCKS + TBLOCKS + 9, 256, 0, stream>>>(x, xb, (int)NTOK,
        Wq, Wk, Wv, Wo, bq, bk, bv, wqkvT, woT, bqkv);

    dim3 g1(128, 18);
    k_gemm<0><<<g1, 256, 0, stream>>>(xb, wqkvT, bqkv, qb, kb, vb, nullptr);

    k_transpose_v<<<3072, 256, 0, stream>>>(vb, vtb);
    k_attn<<<1536, 256, 0, stream>>>(qb, kb, vtb, ctx);

    dim3 g2(128, 6);
    k_gemm<1><<<g2, 256, 0, stream>>>(ctx, woT, bo, nullptr, nullptr, nullptr, out);
}

// Round 9
// 303.670 us; speedup vs baseline: 1.0843x; 1.0843x over previous
//
#include <hip/hip_runtime.h>
#include <hip/hip_bf16.h>
#include <cstdint>
#include <cstddef>

typedef unsigned short u16;
typedef __attribute__((ext_vector_type(8))) short s8v;    // 8 x bf16 = 4 VGPR
typedef __attribute__((ext_vector_type(4))) float f4v;    // 16x16 MFMA acc
typedef __attribute__((ext_vector_type(8))) u16 u16x8;
typedef __attribute__((ext_vector_type(4))) uint32_t u32x4;

#define AS1 __attribute__((address_space(1)))
#define AS3 __attribute__((address_space(3)))

// ---- constants ----
#define BATCH 16
#define SEQ   1024
#define EMBED 768
#define HEADS 12
#define DH    64
#define MTOT  (BATCH*SEQ)       // 16384
// Q pre-scale: 1/sqrt(Dh) * log2(e)  -> scores in log2 domain, p = 2^s via
// bare v_exp_f32 (saves the v_mul inside __expf; one less rounding step).
#define QSCALE 0.1803368867f

__device__ __forceinline__ u16 f2bf(float f) {      // RNE fp32 -> bf16
    union { float f; uint32_t u; } v; v.f = f;
    uint32_t r = v.u + 0x7fffu + ((v.u >> 16) & 1u);
    return (u16)(r >> 16);
}

__device__ __forceinline__ float exp2_hw(float x) {  // v_exp_f32 = 2^x native
    float r;
    asm("v_exp_f32 %0, %1" : "=v"(r) : "v"(x));
    return r;
}

__device__ __forceinline__ void gll16(const u16* g, u16* l) {
    __builtin_amdgcn_global_load_lds((AS1 void*)g, (AS3 void*)l, 16, 0, 0);
}

// ---------------- fused pack ----------------
// x -> bf16 (coalesced); weights transpose+bf16 via 64x64 LDS tiles (round-6
// verified); biases. Wq/bq pre-scaled by QSCALE (1/8 * log2e, round-8).
#define XBLOCKS 12288
#define TBLOCKS 576          // 432 QKV tiles (36 n x 12 k) + 144 Wo tiles (12 x 12)
__global__ void k_pack(const float* __restrict__ x, u16* __restrict__ xb, int nx,
                       const float* __restrict__ Wq, const float* __restrict__ Wk,
                       const float* __restrict__ Wv, const float* __restrict__ Wo,
                       const float* __restrict__ bq, const float* __restrict__ bk,
                       const float* __restrict__ bv,
                       u16* __restrict__ wqkvT, u16* __restrict__ woT,
                       float* __restrict__ bqkv)
{
    __shared__ __attribute__((aligned(16))) u16 ts[64 * 80];
    const int tid = threadIdx.x;
    if (blockIdx.x < XBLOCKS) {
        int i = (blockIdx.x * 256 + tid) * 4;
        if (i + 3 < nx) {
            float4 f = *(const float4*)(x + i);
            ushort4 o;
            o.x = f2bf(f.x); o.y = f2bf(f.y); o.z = f2bf(f.z); o.w = f2bf(f.w);
            *(ushort4*)(xb + i) = o;
        }
        return;
    }
    int tb = blockIdx.x - XBLOCKS;
    if (tb < TBLOCKS) {
        // 64x64 tile transpose: out[n][k] = src[k][nn] * sc (bf16)
        const float* src; u16* dst; int n0, k0, nn0; float sc;
        if (tb < 432) {
            int nt = tb % 36, kt = tb / 36;
            n0 = nt * 64; k0 = kt * 64; dst = wqkvT;
            if (n0 < 768)       { src = Wq; nn0 = n0;        sc = QSCALE; }
            else if (n0 < 1536) { src = Wk; nn0 = n0 - 768;  sc = 1.0f;   }
            else                { src = Wv; nn0 = n0 - 1536; sc = 1.0f;   }
        } else {
            int tb2 = tb - 432;
            int nt = tb2 % 12, kt = tb2 / 12;
            n0 = nt * 64; k0 = kt * 64; nn0 = n0; sc = 1.0f;
            src = Wo; dst = woT;
        }
        const int r = tid >> 2, cb = (tid & 3) * 16;
#pragma unroll
        for (int i = 0; i < 4; ++i) {
            float4 f = *(const float4*)(src + (size_t)(k0 + r) * 768 + nn0 + cb + i * 4);
            ts[(cb + i * 4 + 0) * 80 + r] = f2bf(f.x * sc);
            ts[(cb + i * 4 + 1) * 80 + r] = f2bf(f.y * sc);
            ts[(cb + i * 4 + 2) * 80 + r] = f2bf(f.z * sc);
            ts[(cb + i * 4 + 3) * 80 + r] = f2bf(f.w * sc);
        }
        __syncthreads();
#pragma unroll
        for (int j = 0; j < 2; ++j) {
            u16x8 tv = *(const u16x8*)(ts + r * 80 + cb + j * 8);
            *(u16x8*)(dst + (size_t)(n0 + r) * 768 + k0 + cb + j * 8) = tv;
        }
        return;
    }
    int t3 = (tb - TBLOCKS) * 256 + tid;
    if (t3 < 2304) {
        bqkv[t3] = (t3 < 768) ? bq[t3] * QSCALE
                 : ((t3 < 1536) ? bk[t3 - 768] : bv[t3 - 1536]);
    }
}

// ---------------- GEMM: C[M x N] = A[M x 768] * BT[N x 768]^T + bias ----------------
// Round-7 verified: 128x128 tile, BK=64 (12 K-steps), 256 thr, 32 MFMA/K-step,
// XOR-swizzled staging (pre-swizzled global source, linear gll16 dest).
template<int MODE>
__global__ __launch_bounds__(256) void k_gemm(
    const u16* __restrict__ A, const u16* __restrict__ BT,
    const float* __restrict__ bias,
    u16* __restrict__ oq, u16* __restrict__ okk, u16* __restrict__ ov,
    float* __restrict__ of)
{
    __shared__ __attribute__((aligned(16))) u16 As[128 * 64];   // 16 KB
    __shared__ __attribute__((aligned(16))) u16 Bs[128 * 64];   // 16 KB
    const int tid = threadIdx.x;
    const int m0 = blockIdx.x * 128;
    const int n0 = blockIdx.y * 128;
    const int wv = tid >> 6;
    const int ln = tid & 63;
    const int l15 = ln & 15, quad = ln >> 4;
    const int wm = (wv >> 1) * 64, wn = (wv & 1) * 64;

    const int srow = tid >> 3;
    const int schnk = ((tid & 7) ^ (srow & 7)) * 8;
    const u16* gA = A + (size_t)(m0 + srow) * 768 + schnk;
    const u16* gB = BT + (size_t)(n0 + srow) * 768 + schnk;
    u16* lA = As + wv * 512;
    u16* lB = Bs + wv * 512;

    const int sl0 = ((quad)     ^ (l15 & 7)) * 8;   // k-half 0 (k 0..31)
    const int sl1 = ((4 + quad) ^ (l15 & 7)) * 8;   // k-half 1 (k 32..63)

    f4v acc[4][4] = {};

    for (int kt = 0; kt < 12; ++kt) {
        const int ko = kt * 64;
#pragma unroll
        for (int i = 0; i < 4; ++i) {
            gll16(gA + (size_t)i * 32 * 768 + ko, lA + i * 2048);
            gll16(gB + (size_t)i * 32 * 768 + ko, lB + i * 2048);
        }
        __syncthreads();

        s8v aF[4][2];
#pragma unroll
        for (int i = 0; i < 4; ++i) {
            const u16* base = As + (wm + i * 16 + l15) * 64;
            aF[i][0] = *(const s8v*)(base + sl0);
            aF[i][1] = *(const s8v*)(base + sl1);
        }
#pragma unroll
        for (int j = 0; j < 4; ++j) {
            const u16* base = Bs + (wn + j * 16 + l15) * 64;
            s8v bF0 = *(const s8v*)(base + sl0);
            s8v bF1 = *(const s8v*)(base + sl1);
#pragma unroll
            for (int i = 0; i < 4; ++i) {
                acc[i][j] = __builtin_amdgcn_mfma_f32_16x16x32_bf16(aF[i][0], bF0, acc[i][j], 0, 0, 0);
                acc[i][j] = __builtin_amdgcn_mfma_f32_16x16x32_bf16(aF[i][1], bF1, acc[i][j], 0, 0, 0);
            }
        }
        __syncthreads();
    }

    // epilogue: C/D layout col = l15, row = quad*4 + reg (verified)
#pragma unroll
    for (int j = 0; j < 4; ++j) {
        int n = n0 + wn + j * 16 + l15;
        float bs = bias[n];
        if (MODE == 0) {
            u16* dst; int nn;
            if (n < 768)       { dst = oq;  nn = n; }
            else if (n < 1536) { dst = okk; nn = n - 768; }
            else               { dst = ov;  nn = n - 1536; }
#pragma unroll
            for (int i = 0; i < 4; ++i) {
                int mrow = m0 + wm + i * 16 + quad * 4;
#pragma unroll
                for (int rg = 0; rg < 4; ++rg)
                    dst[(size_t)(mrow + rg) * 768 + nn] = f2bf(acc[i][j][rg] + bs);
            }
        } else {
#pragma unroll
            for (int i = 0; i < 4; ++i) {
                int mrow = m0 + wm + i * 16 + quad * 4;
#pragma unroll
                for (int rg = 0; rg < 4; ++rg)
                    of[(size_t)(mrow + rg) * 768 + n] = acc[i][j][rg] + bs;
            }
        }
    }
}

// ---------------- V transpose: (192,1024,64) -> (192,64,1024) ----------------
__global__ void k_transpose_v(const u16* __restrict__ v, u16* __restrict__ vt) {
    __shared__ __attribute__((aligned(16))) u16 ts[64 * 80];
    int g = blockIdx.x >> 4;
    int l0 = (blockIdx.x & 15) << 6;
    const u16* vg = v + (size_t)g * 65536;
    u16* vtg = vt + (size_t)g * 65536;
    int tid = threadIdx.x;
#pragma unroll
    for (int c = tid; c < 512; c += 256) {
        int l = c >> 3, d0 = (c & 7) * 8;
        *(uint4*)(ts + l * 80 + d0) = *(const uint4*)(vg + (size_t)(l0 + l) * 64 + d0);
    }
    __syncthreads();
#pragma unroll
    for (int c = tid; c < 512; c += 256) {
        int d = c >> 3, lc = (c & 7) * 8;
        u16x8 tv;
#pragma unroll
        for (int i = 0; i < 8; ++i) tv[i] = ts[(lc + i) * 80 + d];
        *(u16x8*)(vtg + (size_t)d * 1024 + l0 + lc) = tv;
    }
}

// ---------------- flash attention per (group, 128-row q-tile) ----------------
// Round-8 (resubmit; round-8 bench was an infra failure, kernel unchanged):
//  - p = 2^s via bare v_exp_f32 (log2e folded into Q pre-scale).
//  - row sums via ones-column MFMA (Vts row 64 = 1.0; only output col 0 read).
//  - XCD swizzle (T1): 8 consecutive same-XCD slots = 8 q-tiles of one group.
#define KS2(r_, c_) ( ((r_) << 6) + (((((c_) >> 3) ^ ((r_) & 7)) & 7) << 3) + ((c_) & 7) )

__global__ __launch_bounds__(256) void k_attn(
    const u16* __restrict__ qb, const u16* __restrict__ kb,
    const u16* __restrict__ vt, u16* __restrict__ ctx)
{
    __shared__ __attribute__((aligned(16))) u16 Ks[128 * 64];    // 16 KB, XOR-swizzled
    __shared__ __attribute__((aligned(16))) u16 Vts[80 * 136];   // 21760 B (row 64 = ones)

    const int bid = blockIdx.x;
    const int xr = bid & 7, bt = bid >> 3;       // 1536 blocks = 8 XCD x 192
    const int g = xr * 24 + (bt >> 3);           // 24 groups per XCD residue
    const int q0 = (bt & 7) << 7;
    const int tid = threadIdx.x, wv = tid >> 6;
    const int ln = tid & 63, l15 = ln & 15, quad = ln >> 4;
    const u16* qg = qb + (size_t)g * 65536;
    const u16* kg = kb + (size_t)g * 65536;
    const u16* vtg = vt + (size_t)g * 65536;

    const int krr = tid >> 3, kcb = (tid & 7) * 8;       // K: +i*32 rows
    const int vd = tid >> 4, vc0 = (tid & 15) * 8;       // Vt: +i*16 d-rows
    const u16* kgp = kg + (size_t)krr * 64 + kcb;
    const u16* vgp = vtg + (size_t)vd * 1024 + vc0;

    uint4 kr0 = *(const uint4*)(kgp);
    uint4 kr1 = *(const uint4*)(kgp + 2048);
    uint4 kr2 = *(const uint4*)(kgp + 4096);
    uint4 kr3 = *(const uint4*)(kgp + 6144);
    uint4 vr0 = *(const uint4*)(vgp);
    uint4 vr1 = *(const uint4*)(vgp + 16384);
    uint4 vr2 = *(const uint4*)(vgp + 32768);
    uint4 vr3 = *(const uint4*)(vgp + 49152);

    // ones row (V-ext row 64): 128 cols of bf16 1.0; persists across tiles
    if (tid < 16) {
        uint4 ones;
        ones.x = 0x3F803F80u; ones.y = 0x3F803F80u;
        ones.z = 0x3F803F80u; ones.w = 0x3F803F80u;
        *(uint4*)(Vts + 64 * 136 + tid * 8) = ones;
    }

    const u16* qrow = qg + (size_t)(q0 + wv * 32 + l15) * 64 + quad * 8;
    s8v aQ00 = *(const s8v*)qrow;
    s8v aQ01 = *(const s8v*)(qrow + 32);
    s8v aQ10 = *(const s8v*)(qrow + 1024);        // +16 rows * 64
    s8v aQ11 = *(const s8v*)(qrow + 1024 + 32);

    f4v o0[4] = {}, o1[4] = {};
    f4v o4_0 = {}, o4_1 = {};                     // ones-column row sums

    for (int jt = 0; jt < 8; ++jt) {
        __builtin_amdgcn_s_barrier();
        __builtin_amdgcn_sched_barrier(0);

        *(uint4*)(Ks + KS2(krr,      kcb)) = kr0;
        *(uint4*)(Ks + KS2(krr + 32, kcb)) = kr1;
        *(uint4*)(Ks + KS2(krr + 64, kcb)) = kr2;
        *(uint4*)(Ks + KS2(krr + 96, kcb)) = kr3;
        *(uint4*)(Vts + (vd     ) * 136 + vc0) = vr0;
        *(uint4*)(Vts + (vd + 16) * 136 + vc0) = vr1;
        *(uint4*)(Vts + (vd + 32) * 136 + vc0) = vr2;
        *(uint4*)(Vts + (vd + 48) * 136 + vc0) = vr3;

        if (jt < 7) {
            const size_t koff = (size_t)(jt + 1) * 8192;   // 128 rows * 64
            const int voff = (jt + 1) * 128;
            kr0 = *(const uint4*)(kgp + koff);
            kr1 = *(const uint4*)(kgp + koff + 2048);
            kr2 = *(const uint4*)(kgp + koff + 4096);
            kr3 = *(const uint4*)(kgp + koff + 6144);
            vr0 = *(const uint4*)(vgp + voff);
            vr1 = *(const uint4*)(vgp + voff + 16384);
            vr2 = *(const uint4*)(vgp + voff + 32768);
            vr3 = *(const uint4*)(vgp + voff + 49152);
        }

        asm volatile("s_waitcnt lgkmcnt(0)" ::: "memory");
        __builtin_amdgcn_s_barrier();
        __builtin_amdgcn_sched_barrier(0);

        // swapped QK^T: each K-frag pair feeds BOTH q-sets
        f4v s0[8], s1[8];
        __builtin_amdgcn_s_setprio(1);
#pragma unroll
        for (int ns = 0; ns < 8; ++ns) {
            int rK = ns * 16 + l15;
            s8v b0 = *(const s8v*)(Ks + KS2(rK, quad * 8));
            s8v b1 = *(const s8v*)(Ks + KS2(rK, quad * 8 + 32));
            f4v t0 = {};
            t0 = __builtin_amdgcn_mfma_f32_16x16x32_bf16(b0, aQ00, t0, 0, 0, 0);
            t0 = __builtin_amdgcn_mfma_f32_16x16x32_bf16(b1, aQ01, t0, 0, 0, 0);
            s0[ns] = t0;
            f4v t1 = {};
            t1 = __builtin_amdgcn_mfma_f32_16x16x32_bf16(b0, aQ10, t1, 0, 0, 0);
            t1 = __builtin_amdgcn_mfma_f32_16x16x32_bf16(b1, aQ11, t1, 0, 0, 0);
            s1[ns] = t1;
        }
        __builtin_amdgcn_s_setprio(0);

        // p = 2^s (scores already in log2 domain); NO scalar row-sum adds
        s8v aP0[4], aP1[4];
#pragma unroll
        for (int ns = 0; ns < 8; ++ns)
#pragma unroll
            for (int rg = 0; rg < 4; ++rg)
                s0[ns][rg] = exp2_hw(s0[ns][rg]);
#pragma unroll
        for (int ks = 0; ks < 4; ++ks) {
            uint32_t a0, a1, c0, c1;
            asm("v_cvt_pk_bf16_f32 %0, %1, %2" : "=v"(a0) : "v"(s0[2*ks][0]),   "v"(s0[2*ks][1]));
            asm("v_cvt_pk_bf16_f32 %0, %1, %2" : "=v"(a1) : "v"(s0[2*ks][2]),   "v"(s0[2*ks][3]));
            asm("v_cvt_pk_bf16_f32 %0, %1, %2" : "=v"(c0) : "v"(s0[2*ks+1][0]), "v"(s0[2*ks+1][1]));
            asm("v_cvt_pk_bf16_f32 %0, %1, %2" : "=v"(c1) : "v"(s0[2*ks+1][2]), "v"(s0[2*ks+1][3]));
            asm("v_permlane32_swap_b32 %0, %1" : "+v"(a0), "+v"(c0));
            asm("v_permlane16_swap_b32 %0, %1" : "+v"(a0), "+v"(c0));
            asm("v_permlane32_swap_b32 %0, %1" : "+v"(a1), "+v"(c1));
            asm("v_permlane16_swap_b32 %0, %1" : "+v"(a1), "+v"(c1));
            u32x4 pk; pk.x = a0; pk.y = a1; pk.z = c0; pk.w = c1;
            aP0[ks] = __builtin_bit_cast(s8v, pk);
        }
#pragma unroll
        for (int ns = 0; ns < 8; ++ns)
#pragma unroll
            for (int rg = 0; rg < 4; ++rg)
                s1[ns][rg] = exp2_hw(s1[ns][rg]);
#pragma unroll
        for (int ks = 0; ks < 4; ++ks) {
            uint32_t a0, a1, c0, c1;
            asm("v_cvt_pk_bf16_f32 %0, %1, %2" : "=v"(a0) : "v"(s1[2*ks][0]),   "v"(s1[2*ks][1]));
            asm("v_cvt_pk_bf16_f32 %0, %1, %2" : "=v"(a1) : "v"(s1[2*ks][2]),   "v"(s1[2*ks][3]));
            asm("v_cvt_pk_bf16_f32 %0, %1, %2" : "=v"(c0) : "v"(s1[2*ks+1][0]), "v"(s1[2*ks+1][1]));
            asm("v_cvt_pk_bf16_f32 %0, %1, %2" : "=v"(c1) : "v"(s1[2*ks+1][2]), "v"(s1[2*ks+1][3]));
            asm("v_permlane32_swap_b32 %0, %1" : "+v"(a0), "+v"(c0));
            asm("v_permlane16_swap_b32 %0, %1" : "+v"(a0), "+v"(c0));
            asm("v_permlane32_swap_b32 %0, %1" : "+v"(a1), "+v"(c1));
            asm("v_permlane16_swap_b32 %0, %1" : "+v"(a1), "+v"(c1));
            u32x4 pk; pk.x = a0; pk.y = a1; pk.z = c0; pk.w = c1;
            aP1[ks] = __builtin_bit_cast(s8v, pk);
        }

        // O += P V ; 5th ds-block (V-ext ones row) accumulates row sums
        __builtin_amdgcn_s_setprio(1);
#pragma unroll
        for (int ks = 0; ks < 4; ++ks) {
#pragma unroll
            for (int ds = 0; ds < 4; ++ds) {
                s8v bV = *(const s8v*)(Vts + (ds * 16 + l15) * 136 + ks * 32 + quad * 8);
                o0[ds] = __builtin_amdgcn_mfma_f32_16x16x32_bf16(aP0[ks], bV, o0[ds], 0, 0, 0);
                o1[ds] = __builtin_amdgcn_mfma_f32_16x16x32_bf16(aP1[ks], bV, o1[ds], 0, 0, 0);
            }
            s8v bV4 = *(const s8v*)(Vts + (64 + l15) * 136 + ks * 32 + quad * 8);
            o4_0 = __builtin_amdgcn_mfma_f32_16x16x32_bf16(aP0[ks], bV4, o4_0, 0, 0, 0);
            o4_1 = __builtin_amdgcn_mfma_f32_16x16x32_bf16(aP1[ks], bV4, o4_1, 0, 0, 0);
        }
        __builtin_amdgcn_s_setprio(0);
    }

    // row sums live in o4_s[rg] at lanes with l15==0 (C col 0 = ones row 64):
    // lane (quad<<4) holds sum for row quad*4+rg -- exactly this lane's rows.
    const int b = g / 12, h = g % 12;
    u16* cbase = ctx + (size_t)b * 786432 + h * 64;
#pragma unroll
    for (int rg = 0; rg < 4; ++rg) {
        int row0 = q0 + wv * 32 + quad * 4 + rg;
        float inv0 = 1.0f / __shfl(o4_0[rg], quad << 4, 64);
#pragma unroll
        for (int ds = 0; ds < 4; ++ds)
            cbase[(size_t)row0 * 768 + ds * 16 + l15] = f2bf(o0[ds][rg] * inv0);
        int row1 = row0 + 16;
        float inv1 = 1.0f / __shfl(o4_1[rg], quad << 4, 64);
#pragma unroll
        for (int ds = 0; ds < 4; ++ds)
            cbase[(size_t)row1 * 768 + ds * 16 + l15] = f2bf(o1[ds][rg] * inv1);
    }
}

// ---------------- launcher ----------------
extern "C" void kernel_launch(void* const* d_in, const int* in_sizes, int n_in,
                              void* d_out, int out_size, void* d_ws, size_t ws_size,
                              hipStream_t stream) {
    const float* x  = (const float*)d_in[0];
    const float* Wq = (const float*)d_in[1];
    const float* bq = (const float*)d_in[2];
    const float* Wk = (const float*)d_in[3];
    const float* bk = (const float*)d_in[4];
    const float* Wv = (const float*)d_in[5];
    const float* bv = (const float*)d_in[6];
    const float* Wo = (const float*)d_in[7];
    const float* bo = (const float*)d_in[8];
    float* out = (float*)d_out;

    const size_t NTOK = (size_t)MTOT * EMBED;          // 12,582,912
    char* w = (char*)d_ws;
    u16* xb    = (u16*)w;              w += NTOK * 2;  // x bf16; reused as ctx
    u16* qb    = (u16*)w;              w += NTOK * 2;
    u16* kb    = (u16*)w;              w += NTOK * 2;
    u16* vb    = (u16*)w;              w += NTOK * 2;
    u16* vtb   = (u16*)w;              w += NTOK * 2;
    u16* wqkvT = (u16*)w;              w += (size_t)2304 * 768 * 2;
    u16* woT   = (u16*)w;              w += (size_t)768 * 768 * 2;
    float* bqkv = (float*)w;           w += 2304 * 4;
    u16* ctx = xb;                                      // reuse (x dead after GEMM1)

    k_pack<<<XBLOCKS + TBLOCKS + 9, 256, 0, stream>>>(x, xb, (int)NTOK,
        Wq, Wk, Wv, Wo, bq, bk, bv, wqkvT, woT, bqkv);

    dim3 g1(128, 18);
    k_gemm<0><<<g1, 256, 0, stream>>>(xb, wqkvT, bqkv, qb, kb, vb, nullptr);

    k_transpose_v<<<3072, 256, 0, stream>>>(vb, vtb);
    k_attn<<<1536, 256, 0, stream>>>(qb, kb, vtb, ctx);

    dim3 g2(128, 6);
    k_gemm<1><<<g2, 256, 0, stream>>>(ctx, woT, bo, nullptr, nullptr, nullptr, out);
}